// Round 11
// baseline (33091.992 us; speedup 1.0000x reference)
//
#include <hip/hip_runtime.h>
#include <math.h>

// ---------------------------------------------------------------------------
// NeuralMemory (Titans-style). Round 10/11: persistent scan, FENCE-FREE.
// History: r2/r8 persistent kernel w/ __threadfence barriers: ~45us/barrier
// (per-wave L2 writeback/invalidate, invariant to poll topology). r9 used
// kernel boundaries as barriers: 10.5us/dispatch (packet-processor L2 flush)
// -> 23.1ms total. This round: persistent kernel again, but ALL cross-WG data
// (h1g, dOg) moves via agent-scope RELAXED atomics, which execute at the
// coherent LLC point -- no cache maintenance instructions at all. The
// data->flag ordering comes from the s_waitcnt vmcnt(0) that __syncthreads()
// emits before s_barrier. Barrier = master/broadcast flags (identical to r8).
// Predicted: ~2-4us/barrier -> scan 6-11ms.
// B=8, S=1024, D=768, GH=32, THETA=0.01
// ---------------------------------------------------------------------------

#define S_LEN 1024
#define D_DIM 768
#define B_SZ 8
#define NWG 256      // scan workgroups (1 row of each matrix per wave, 3 waves)
#define NTHR 192     // 3 waves
#define THETA_F 0.01f
#define FLAG_STRIDE 16   // one 64B cacheline per arrival flag

__device__ __forceinline__ void st_agent(float* p, float v) {
  __hip_atomic_store(p, v, __ATOMIC_RELAXED, __HIP_MEMORY_SCOPE_AGENT);
}
__device__ __forceinline__ float ld_agent(const float* p) {
  return __hip_atomic_load(p, __ATOMIC_RELAXED, __HIP_MEMORY_SCOPE_AGENT);
}

// ---------------------------------------------------------------------------
// Generic f32 GEMM (unchanged since round 2; validated)
// C[n,e] = act( sum_d A[n,d]*W[e,d] + bias[e] )
// ---------------------------------------------------------------------------
template <int ACT, int REMAP>
__global__ __launch_bounds__(256) void gemm_tn(const float* __restrict__ A,
                                               const float* __restrict__ W,
                                               const float* __restrict__ bias,
                                               float* __restrict__ C) {
  __shared__ float As[16][132];
  __shared__ float Ws[16][68];
  const int tid = threadIdx.x;
  const int txx = tid & 15, tyy = tid >> 4;
  const int eb = blockIdx.x * 64;
  const int nb = blockIdx.y * 128;
  float acc[8][4];
#pragma unroll
  for (int i = 0; i < 8; ++i)
#pragma unroll
    for (int j = 0; j < 4; ++j) acc[i][j] = 0.f;

  const int lr = tid >> 2;          // 0..63
  const int lc = (tid & 3) << 2;    // 0,4,8,12

  for (int k0 = 0; k0 < 768; k0 += 16) {
    float4 a0 = *(const float4*)(A + (size_t)(nb + lr) * 768 + k0 + lc);
    float4 a1 = *(const float4*)(A + (size_t)(nb + lr + 64) * 768 + k0 + lc);
    float4 wv = *(const float4*)(W + (size_t)(eb + lr) * 768 + k0 + lc);
    __syncthreads();
    As[lc + 0][lr] = a0.x; As[lc + 1][lr] = a0.y; As[lc + 2][lr] = a0.z; As[lc + 3][lr] = a0.w;
    As[lc + 0][lr + 64] = a1.x; As[lc + 1][lr + 64] = a1.y; As[lc + 2][lr + 64] = a1.z; As[lc + 3][lr + 64] = a1.w;
    Ws[lc + 0][lr] = wv.x; Ws[lc + 1][lr] = wv.y; Ws[lc + 2][lr] = wv.z; Ws[lc + 3][lr] = wv.w;
    __syncthreads();
#pragma unroll
    for (int kk = 0; kk < 16; ++kk) {
      float4 x0 = *(const float4*)(&As[kk][tyy * 8]);
      float4 x1 = *(const float4*)(&As[kk][tyy * 8 + 4]);
      float4 y0 = *(const float4*)(&Ws[kk][txx * 4]);
      float a8[8] = {x0.x, x0.y, x0.z, x0.w, x1.x, x1.y, x1.z, x1.w};
      float b4[4] = {y0.x, y0.y, y0.z, y0.w};
#pragma unroll
      for (int i = 0; i < 8; ++i)
#pragma unroll
        for (int j = 0; j < 4; ++j) acc[i][j] = fmaf(a8[i], b4[j], acc[i][j]);
    }
  }
  float4 bv = *(const float4*)(bias + eb + txx * 4);
#pragma unroll
  for (int i = 0; i < 8; ++i) {
    int n = nb + tyy * 8 + i;
    float4 o;
    o.x = acc[i][0] + bv.x; o.y = acc[i][1] + bv.y;
    o.z = acc[i][2] + bv.z; o.w = acc[i][3] + bv.w;
    if (ACT == 1) {
      o.x = o.x / (1.f + expf(-o.x));
      o.y = o.y / (1.f + expf(-o.y));
      o.z = o.z / (1.f + expf(-o.z));
      o.w = o.w / (1.f + expf(-o.w));
    }
    size_t row = REMAP ? (size_t)((n & 1023) * 8 + (n >> 10)) : (size_t)n;
    *(float4*)(C + row * 768 + eb + txx * 4) = o;
  }
}

// ---------------------------------------------------------------------------
// Gate scalars (unchanged; validated)
// ---------------------------------------------------------------------------
__global__ __launch_bounds__(512) void gates_kernel(
    const float* __restrict__ x, const float* __restrict__ FGW1,
    const float* __restrict__ FGb1, const float* __restrict__ FGw2,
    const float* __restrict__ FGb2, const float* __restrict__ DGW1,
    const float* __restrict__ DGb1, const float* __restrict__ DGw2,
    const float* __restrict__ DGb2, float* __restrict__ alphaA,
    float* __restrict__ etaA) {
  __shared__ float sA[8], sE[8];
  const int t = blockIdx.x, tid = threadIdx.x;
  const int b = tid >> 6, lane = tid & 63;
  const bool isFG = lane < 32;
  const int h = lane & 31;
  const float* xr = x + ((size_t)b * S_LEN + t) * D_DIM;
  const float* Wr = (isFG ? FGW1 : DGW1) + (size_t)h * D_DIM;
  float acc = 0.f;
  for (int d = 0; d < D_DIM; d += 4) {
    float4 xv = *(const float4*)(xr + d);
    float4 wv = *(const float4*)(Wr + d);
    acc = fmaf(xv.x, wv.x, acc);
    acc = fmaf(xv.y, wv.y, acc);
    acc = fmaf(xv.z, wv.z, acc);
    acc = fmaf(xv.w, wv.w, acc);
  }
  float z = acc + (isFG ? FGb1[h] : DGb1[h]);
  float sg = 1.f / (1.f + expf(-z));
  float p = z * sg * (isFG ? FGw2[h] : DGw2[h]);
#pragma unroll
  for (int off = 16; off > 0; off >>= 1) p += __shfl_xor(p, off, 64);
  if (lane == 0) sA[b] = 1.f / (1.f + expf(-(p + FGb2[0])));
  if (lane == 32) sE[b] = 1.f / (1.f + expf(-(p + DGb2[0])));
  __syncthreads();
  if (tid == 0) {
    float sa = 0.f, se = 0.f;
#pragma unroll
    for (int i = 0; i < 8; ++i) { sa += sA[i]; se += sE[i]; }
    alphaA[t] = sa * 0.125f;
    etaA[t] = se * 0.125f;
  }
}

// ---------------------------------------------------------------------------
// Master/broadcast grid barrier, monotone epochs. NO FENCES: all shared data
// moves via agent-scope atomics (coherent at LLC); __syncthreads() emits
// s_waitcnt vmcnt(0) before s_barrier, so a WG's data stores are complete
// before tid0 publishes its arrival flag.
// ---------------------------------------------------------------------------
__device__ __forceinline__ void grid_barrier(int* arrive, int* go, int wg,
                                             int tid, int epoch) {
  __syncthreads();   // join WG; drains each wave's outstanding stores (vmcnt)
  if (wg == 0) {
#pragma unroll 1
    for (int s = tid + 1; s < NWG; s += NTHR) {
      while (__hip_atomic_load(arrive + s * FLAG_STRIDE, __ATOMIC_RELAXED,
                               __HIP_MEMORY_SCOPE_AGENT) < epoch) {
        __builtin_amdgcn_s_sleep(1);
      }
    }
    __syncthreads();
    if (tid == 0)
      __hip_atomic_store(go, epoch, __ATOMIC_RELAXED,
                         __HIP_MEMORY_SCOPE_AGENT);
  } else {
    if (tid == 0) {
      __hip_atomic_store(arrive + wg * FLAG_STRIDE, epoch, __ATOMIC_RELAXED,
                         __HIP_MEMORY_SCOPE_AGENT);
      while (__hip_atomic_load(go, __ATOMIC_RELAXED,
                               __HIP_MEMORY_SCOPE_AGENT) < epoch) {
        __builtin_amdgcn_s_sleep(1);
      }
    }
    __syncthreads();
  }
}

// ---------------------------------------------------------------------------
// Persistent scan kernel. 256 WGs x 192 thr (3 waves). Wave r of WG wg owns
// row jg = wg*3+r of: W1, S1, W2, S2 (row-major) and W2T, S2T (LDS-private).
// Cross-WG arrays h1g/dOg are accessed ONLY via agent-scope atomics.
// Per step t: A (h1) -> barrier -> B (out/dOut, W2 update) -> barrier ->
// C (dh1, W1/W2T updates).
// ---------------------------------------------------------------------------
__global__ __launch_bounds__(NTHR, 1) void scan_kernel(
    const float* __restrict__ kbuf, const float* __restrict__ vbuf,
    const float* __restrict__ alphaA, const float* __restrict__ etaA,
    const float* __restrict__ MW1, const float* __restrict__ Mb1,
    const float* __restrict__ MW2, const float* __restrict__ Mb2,
    float* __restrict__ W1f, float* __restrict__ b1f, float* __restrict__ W2f,
    float* __restrict__ b2f, float* h1g, float* dOg,
    int* arrive, int* go) {
  __shared__ float sW1[3][768], sS1[3][768], sW2[3][768], sS2[3][768];
  __shared__ float sW2T[3][768], sS2T[3][768];
  __shared__ float sb1[3], ssb1[3], sb2[3], ssb2[3];

  const int tid = threadIdx.x, wg = blockIdx.x;
  const int r = tid >> 6, lane = tid & 63;
  const int jg = wg * 3 + r;
  const int colb = lane * 12;

  // ---- init state ----
  {
    const float4* s1 = (const float4*)(MW1 + (size_t)jg * 768 + colb);
    float4* d1 = (float4*)(&sW1[r][colb]);
    d1[0] = s1[0]; d1[1] = s1[1]; d1[2] = s1[2];
    const float4* s2 = (const float4*)(MW2 + (size_t)jg * 768 + colb);
    float4* d2 = (float4*)(&sW2[r][colb]);
    d2[0] = s2[0]; d2[1] = s2[1]; d2[2] = s2[2];
#pragma unroll
    for (int m = 0; m < 12; ++m)
      sW2T[r][colb + m] = MW2[(size_t)(colb + m) * 768 + jg];
    float4 z4 = {0.f, 0.f, 0.f, 0.f};
    ((float4*)&sS1[r][colb])[0] = z4; ((float4*)&sS1[r][colb])[1] = z4; ((float4*)&sS1[r][colb])[2] = z4;
    ((float4*)&sS2[r][colb])[0] = z4; ((float4*)&sS2[r][colb])[1] = z4; ((float4*)&sS2[r][colb])[2] = z4;
    ((float4*)&sS2T[r][colb])[0] = z4; ((float4*)&sS2T[r][colb])[1] = z4; ((float4*)&sS2T[r][colb])[2] = z4;
    if (lane == 0) {
      sb1[r] = Mb1[jg]; sb2[r] = Mb2[jg];
      ssb1[r] = 0.f; ssb2[r] = 0.f;
    }
  }
  __syncthreads();

  int epoch = 0;
  alignas(16) float ktv[8][12];
  float hprev[8], sgv[8], h1loc[8];
  const float c0 = 2.0f / 6144.0f;

  for (int t = 0; t < S_LEN; ++t) {
    const float a_t = alphaA[t], e_t = etaA[t];
    const float om_a = 1.0f - a_t;

    // k_t rows (registers through phase C) -- read-only, normal cached loads
#pragma unroll
    for (int b = 0; b < 8; ++b) {
      const float4* kp =
          (const float4*)(kbuf + ((size_t)t * 8 + b) * 768 + colb);
      float4 k0 = kp[0], k1 = kp[1], k2 = kp[2];
      ktv[b][0] = k0.x; ktv[b][1] = k0.y; ktv[b][2] = k0.z; ktv[b][3] = k0.w;
      ktv[b][4] = k1.x; ktv[b][5] = k1.y; ktv[b][6] = k1.z; ktv[b][7] = k1.w;
      ktv[b][8] = k2.x; ktv[b][9] = k2.y; ktv[b][10] = k2.z; ktv[b][11] = k2.w;
    }

    // ---- phase A ----
    {
      alignas(16) float w1v[12];
      const float4* wp = (const float4*)(&sW1[r][colb]);
      *(float4*)&w1v[0] = wp[0]; *(float4*)&w1v[4] = wp[1]; *(float4*)&w1v[8] = wp[2];
      float acc[8] = {0, 0, 0, 0, 0, 0, 0, 0};
#pragma unroll
      for (int m = 0; m < 12; ++m)
#pragma unroll
        for (int b = 0; b < 8; ++b) acc[b] = fmaf(ktv[b][m], w1v[m], acc[b]);
#pragma unroll
      for (int off = 32; off > 0; off >>= 1)
#pragma unroll
        for (int b = 0; b < 8; ++b) acc[b] += __shfl_xor(acc[b], off, 64);
      const float b1v = sb1[r];
#pragma unroll
      for (int b = 0; b < 8; ++b) {
        float z = acc[b] + b1v;
        float sg = 1.0f / (1.0f + expf(-z));
        hprev[b] = z; sgv[b] = sg; h1loc[b] = z * sg;
      }
#pragma unroll
      for (int b = 0; b < 8; ++b)
        if (lane == b) st_agent(h1g + b * 768 + jg, h1loc[b]);
    }
    grid_barrier(arrive, go, wg, tid, ++epoch);

    // ---- phase B ----
    {
      alignas(16) float w2v[12];
      const float4* wp = (const float4*)(&sW2[r][colb]);
      *(float4*)&w2v[0] = wp[0]; *(float4*)&w2v[4] = wp[1]; *(float4*)&w2v[8] = wp[2];
      float hc[8][12];
#pragma unroll
      for (int b = 0; b < 8; ++b)
#pragma unroll
        for (int m = 0; m < 12; ++m)
          hc[b][m] = ld_agent(h1g + b * 768 + colb + m);
      float acc[8] = {0, 0, 0, 0, 0, 0, 0, 0};
#pragma unroll
      for (int m = 0; m < 12; ++m)
#pragma unroll
        for (int b = 0; b < 8; ++b) acc[b] = fmaf(hc[b][m], w2v[m], acc[b]);
#pragma unroll
      for (int off = 32; off > 0; off >>= 1)
#pragma unroll
        for (int b = 0; b < 8; ++b) acc[b] += __shfl_xor(acc[b], off, 64);
      const float b2v = sb2[r];
      float dOv[8];
#pragma unroll
      for (int b = 0; b < 8; ++b) {
        float outv = acc[b] + b2v;
        dOv[b] = c0 * (outv - vbuf[((size_t)t * 8 + b) * 768 + jg]);
      }
#pragma unroll
      for (int b = 0; b < 8; ++b)
        if (lane == b) st_agent(dOg + b * 768 + jg, dOv[b]);
      // W2 row update
#pragma unroll
      for (int m = 0; m < 12; ++m) {
        float g = 0.f;
#pragma unroll
        for (int b = 0; b < 8; ++b) g = fmaf(dOv[b], hc[b][m], g);
        float snew = e_t * sS2[r][colb + m] - THETA_F * g;
        sS2[r][colb + m] = snew;
        sW2[r][colb + m] = om_a * w2v[m] + snew;
      }
      if (lane == 0) {
        float gb = dOv[0] + dOv[1] + dOv[2] + dOv[3] + dOv[4] + dOv[5] + dOv[6] + dOv[7];
        float snew = e_t * ssb2[r] - THETA_F * gb;
        ssb2[r] = snew;
        sb2[r] = om_a * sb2[r] + snew;
      }
    }
    grid_barrier(arrive, go, wg, tid, ++epoch);

    // ---- phase C ----
    {
      alignas(16) float w2tv[12];
      const float4* wp = (const float4*)(&sW2T[r][colb]);
      *(float4*)&w2tv[0] = wp[0]; *(float4*)&w2tv[4] = wp[1]; *(float4*)&w2tv[8] = wp[2];
      float dc[8][12];
#pragma unroll
      for (int b = 0; b < 8; ++b)
#pragma unroll
        for (int m = 0; m < 12; ++m)
          dc[b][m] = ld_agent(dOg + b * 768 + colb + m);
      float acc[8] = {0, 0, 0, 0, 0, 0, 0, 0};
#pragma unroll
      for (int m = 0; m < 12; ++m)
#pragma unroll
        for (int b = 0; b < 8; ++b) acc[b] = fmaf(dc[b][m], w2tv[m], acc[b]);
#pragma unroll
      for (int off = 32; off > 0; off >>= 1)
#pragma unroll
        for (int b = 0; b < 8; ++b) acc[b] += __shfl_xor(acc[b], off, 64);
      float dpre[8];
#pragma unroll
      for (int b = 0; b < 8; ++b)
        dpre[b] = acc[b] * (sgv[b] * (1.0f + hprev[b] * (1.0f - sgv[b])));
      // W1 row update
#pragma unroll
      for (int m = 0; m < 12; ++m) {
        float g = 0.f;
#pragma unroll
        for (int b = 0; b < 8; ++b) g = fmaf(dpre[b], ktv[b][m], g);
        float snew = e_t * sS1[r][colb + m] - THETA_F * g;
        sS1[r][colb + m] = snew;
        sW1[r][colb + m] = om_a * sW1[r][colb + m] + snew;
      }
      // W2T row update
#pragma unroll
      for (int m = 0; m < 12; ++m) {
        float g = 0.f;
#pragma unroll
        for (int b = 0; b < 8; ++b) g = fmaf(h1loc[b], dc[b][m], g);
        float snew = e_t * sS2T[r][colb + m] - THETA_F * g;
        sS2T[r][colb + m] = snew;
        sW2T[r][colb + m] = om_a * sW2T[r][colb + m] + snew;
      }
      if (lane == 0) {
        float gb = dpre[0] + dpre[1] + dpre[2] + dpre[3] + dpre[4] + dpre[5] + dpre[6] + dpre[7];
        float snew = e_t * ssb1[r] - THETA_F * gb;
        ssb1[r] = snew;
        sb1[r] = om_a * sb1[r] + snew;
      }
    }
    // no barrier before next A (same argument as r2/r8: all reads of h1g done
    // before barrier2; dOg rewritten only after next barrier1)
  }

  // ---- dump final params ----
  {
    float4* d1 = (float4*)(W1f + (size_t)jg * 768 + colb);
    const float4* s1 = (const float4*)(&sW1[r][colb]);
    d1[0] = s1[0]; d1[1] = s1[1]; d1[2] = s1[2];
    float4* d2 = (float4*)(W2f + (size_t)jg * 768 + colb);
    const float4* s2 = (const float4*)(&sW2[r][colb]);
    d2[0] = s2[0]; d2[1] = s2[1]; d2[2] = s2[2];
    if (lane == 0) {
      b1f[jg] = sb1[r];
      b2f[jg] = sb2[r];
    }
  }
}

// ---------------------------------------------------------------------------
extern "C" void kernel_launch(void* const* d_in, const int* in_sizes, int n_in,
                              void* d_out, int out_size, void* d_ws,
                              size_t ws_size, hipStream_t stream) {
  (void)in_sizes; (void)n_in; (void)out_size; (void)ws_size;
  const float* x   = (const float*)d_in[0];
  const float* WKw = (const float*)d_in[1];
  const float* WKb = (const float*)d_in[2];
  const float* WVw = (const float*)d_in[3];
  const float* WVb = (const float*)d_in[4];
  const float* WQw = (const float*)d_in[5];
  const float* WQb = (const float*)d_in[6];
  const float* MW1 = (const float*)d_in[7];
  const float* Mb1 = (const float*)d_in[8];
  const float* MW2 = (const float*)d_in[9];
  const float* Mb2 = (const float*)d_in[10];
  const float* FGW1 = (const float*)d_in[11];
  const float* FGb1 = (const float*)d_in[12];
  const float* FGw2 = (const float*)d_in[13];
  const float* FGb2 = (const float*)d_in[14];
  const float* DGW1 = (const float*)d_in[15];
  const float* DGb1 = (const float*)d_in[16];
  const float* DGw2 = (const float*)d_in[17];
  const float* DGb2 = (const float*)d_in[18];
  float* out = (float*)d_out;

  // workspace layout (floats); q/h1q alias k/v after the scan.
  float* ws = (float*)d_ws;
  float* kbuf = ws;                       // [S,B,D]
  float* vbuf = ws + 6291456;             // [S,B,D]
  float* W1f  = ws + 12582912;            // [768,768]
  float* W2f  = W1f + 589824;
  float* b1f  = W2f + 589824;             // [768]
  float* b2f  = b1f + 768;
  float* alphaA = b2f + 768;              // [1024]
  float* etaA   = alphaA + 1024;
  float* h1g  = etaA + 1024;              // [8,768]
  float* dOg  = h1g + 6144;               // [8,768]
  int* arrive = (int*)(dOg + 6144);       // [NWG*FLAG_STRIDE]
  int* go     = arrive + NWG * FLAG_STRIDE;
  float* qbuf = kbuf;
  float* h1q  = vbuf;

  hipMemsetAsync(arrive, 0, (NWG * FLAG_STRIDE + FLAG_STRIDE) * sizeof(int),
                 stream);

  dim3 gg(12, 64), bb(256);
  gemm_tn<0, 1><<<gg, bb, 0, stream>>>(x, WKw, WKb, kbuf);
  gemm_tn<0, 1><<<gg, bb, 0, stream>>>(x, WVw, WVb, vbuf);
  gates_kernel<<<dim3(1024), dim3(512), 0, stream>>>(
      x, FGW1, FGb1, FGw2, FGb2, DGW1, DGb1, DGw2, DGb2, alphaA, etaA);
  scan_kernel<<<dim3(NWG), dim3(NTHR), 0, stream>>>(
      kbuf, vbuf, alphaA, etaA, MW1, Mb1, MW2, Mb2, W1f, b1f, W2f, b2f, h1g,
      dOg, arrive, go);
  gemm_tn<0, 0><<<gg, bb, 0, stream>>>(x, WQw, WQb, qbuf);
  gemm_tn<1, 0><<<gg, bb, 0, stream>>>(qbuf, W1f, b1f, h1q);
  gemm_tn<0, 0><<<gg, bb, 0, stream>>>(h1q, W2f, b2f, out);
}

// Round 12
// 12568.671 us; speedup vs baseline: 2.6329x; 2.6329x over previous
//
#include <hip/hip_runtime.h>
#include <math.h>

// ---------------------------------------------------------------------------
// NeuralMemory (Titans-style). Round 12: persistent fence-free scan with
// LDS-STAGED tile exchange.
// History: r8 persistent+threadfence: 45us/barrier (L2 wb/inv per wave).
// r9 kernel-boundary sync: 10.5us/dispatch -> 23.1ms. r11 fence-free agent
// atomics: ~30us/step, unstable -- diagnosed as the DATA PATH (96 scalar
// uncached dword loads/thread/phase, latency-bound), not the barrier.
// r12: tiles (h1, dOut; 24KB each) are staged ONCE per WG into LDS via 16
// independent 8B relaxed-agent loads per thread (pipelined), then consumed
// with float4 LDS reads as in r2. Barrier identical to r11 (clean A/B).
// B=8, S=1024, D=768, GH=32, THETA=0.01
// ---------------------------------------------------------------------------

#define S_LEN 1024
#define D_DIM 768
#define B_SZ 8
#define NWG 256      // scan workgroups (1 row of each matrix per wave, 3 waves)
#define NTHR 192     // 3 waves
#define THETA_F 0.01f
#define FLAG_STRIDE 16   // one 64B cacheline per arrival flag

__device__ __forceinline__ void st_agent(float* p, float v) {
  __hip_atomic_store(p, v, __ATOMIC_RELAXED, __HIP_MEMORY_SCOPE_AGENT);
}

// ---------------------------------------------------------------------------
// Generic f32 GEMM (unchanged since round 2; validated)
// C[n,e] = act( sum_d A[n,d]*W[e,d] + bias[e] )
// ---------------------------------------------------------------------------
template <int ACT, int REMAP>
__global__ __launch_bounds__(256) void gemm_tn(const float* __restrict__ A,
                                               const float* __restrict__ W,
                                               const float* __restrict__ bias,
                                               float* __restrict__ C) {
  __shared__ float As[16][132];
  __shared__ float Ws[16][68];
  const int tid = threadIdx.x;
  const int txx = tid & 15, tyy = tid >> 4;
  const int eb = blockIdx.x * 64;
  const int nb = blockIdx.y * 128;
  float acc[8][4];
#pragma unroll
  for (int i = 0; i < 8; ++i)
#pragma unroll
    for (int j = 0; j < 4; ++j) acc[i][j] = 0.f;

  const int lr = tid >> 2;          // 0..63
  const int lc = (tid & 3) << 2;    // 0,4,8,12

  for (int k0 = 0; k0 < 768; k0 += 16) {
    float4 a0 = *(const float4*)(A + (size_t)(nb + lr) * 768 + k0 + lc);
    float4 a1 = *(const float4*)(A + (size_t)(nb + lr + 64) * 768 + k0 + lc);
    float4 wv = *(const float4*)(W + (size_t)(eb + lr) * 768 + k0 + lc);
    __syncthreads();
    As[lc + 0][lr] = a0.x; As[lc + 1][lr] = a0.y; As[lc + 2][lr] = a0.z; As[lc + 3][lr] = a0.w;
    As[lc + 0][lr + 64] = a1.x; As[lc + 1][lr + 64] = a1.y; As[lc + 2][lr + 64] = a1.z; As[lc + 3][lr + 64] = a1.w;
    Ws[lc + 0][lr] = wv.x; Ws[lc + 1][lr] = wv.y; Ws[lc + 2][lr] = wv.z; Ws[lc + 3][lr] = wv.w;
    __syncthreads();
#pragma unroll
    for (int kk = 0; kk < 16; ++kk) {
      float4 x0 = *(const float4*)(&As[kk][tyy * 8]);
      float4 x1 = *(const float4*)(&As[kk][tyy * 8 + 4]);
      float4 y0 = *(const float4*)(&Ws[kk][txx * 4]);
      float a8[8] = {x0.x, x0.y, x0.z, x0.w, x1.x, x1.y, x1.z, x1.w};
      float b4[4] = {y0.x, y0.y, y0.z, y0.w};
#pragma unroll
      for (int i = 0; i < 8; ++i)
#pragma unroll
        for (int j = 0; j < 4; ++j) acc[i][j] = fmaf(a8[i], b4[j], acc[i][j]);
    }
  }
  float4 bv = *(const float4*)(bias + eb + txx * 4);
#pragma unroll
  for (int i = 0; i < 8; ++i) {
    int n = nb + tyy * 8 + i;
    float4 o;
    o.x = acc[i][0] + bv.x; o.y = acc[i][1] + bv.y;
    o.z = acc[i][2] + bv.z; o.w = acc[i][3] + bv.w;
    if (ACT == 1) {
      o.x = o.x / (1.f + expf(-o.x));
      o.y = o.y / (1.f + expf(-o.y));
      o.z = o.z / (1.f + expf(-o.z));
      o.w = o.w / (1.f + expf(-o.w));
    }
    size_t row = REMAP ? (size_t)((n & 1023) * 8 + (n >> 10)) : (size_t)n;
    *(float4*)(C + row * 768 + eb + txx * 4) = o;
  }
}

// ---------------------------------------------------------------------------
// Gate scalars (unchanged; validated)
// ---------------------------------------------------------------------------
__global__ __launch_bounds__(512) void gates_kernel(
    const float* __restrict__ x, const float* __restrict__ FGW1,
    const float* __restrict__ FGb1, const float* __restrict__ FGw2,
    const float* __restrict__ FGb2, const float* __restrict__ DGW1,
    const float* __restrict__ DGb1, const float* __restrict__ DGw2,
    const float* __restrict__ DGb2, float* __restrict__ alphaA,
    float* __restrict__ etaA) {
  __shared__ float sA[8], sE[8];
  const int t = blockIdx.x, tid = threadIdx.x;
  const int b = tid >> 6, lane = tid & 63;
  const bool isFG = lane < 32;
  const int h = lane & 31;
  const float* xr = x + ((size_t)b * S_LEN + t) * D_DIM;
  const float* Wr = (isFG ? FGW1 : DGW1) + (size_t)h * D_DIM;
  float acc = 0.f;
  for (int d = 0; d < D_DIM; d += 4) {
    float4 xv = *(const float4*)(xr + d);
    float4 wv = *(const float4*)(Wr + d);
    acc = fmaf(xv.x, wv.x, acc);
    acc = fmaf(xv.y, wv.y, acc);
    acc = fmaf(xv.z, wv.z, acc);
    acc = fmaf(xv.w, wv.w, acc);
  }
  float z = acc + (isFG ? FGb1[h] : DGb1[h]);
  float sg = 1.f / (1.f + expf(-z));
  float p = z * sg * (isFG ? FGw2[h] : DGw2[h]);
#pragma unroll
  for (int off = 16; off > 0; off >>= 1) p += __shfl_xor(p, off, 64);
  if (lane == 0) sA[b] = 1.f / (1.f + expf(-(p + FGb2[0])));
  if (lane == 32) sE[b] = 1.f / (1.f + expf(-(p + DGb2[0])));
  __syncthreads();
  if (tid == 0) {
    float sa = 0.f, se = 0.f;
#pragma unroll
    for (int i = 0; i < 8; ++i) { sa += sA[i]; se += sE[i]; }
    alphaA[t] = sa * 0.125f;
    etaA[t] = se * 0.125f;
  }
}

// ---------------------------------------------------------------------------
// Master/broadcast grid barrier (byte-identical to r11). No fences: flags are
// agent atomics; tile data moves via agent-atomic loads/stores; __syncthreads
// drains each wave's outstanding stores (vmcnt) before the flag publish.
// ---------------------------------------------------------------------------
__device__ __forceinline__ void grid_barrier(int* arrive, int* go, int wg,
                                             int tid, int epoch) {
  __syncthreads();
  if (wg == 0) {
#pragma unroll 1
    for (int s = tid + 1; s < NWG; s += NTHR) {
      while (__hip_atomic_load(arrive + s * FLAG_STRIDE, __ATOMIC_RELAXED,
                               __HIP_MEMORY_SCOPE_AGENT) < epoch) {
        __builtin_amdgcn_s_sleep(1);
      }
    }
    __syncthreads();
    if (tid == 0)
      __hip_atomic_store(go, epoch, __ATOMIC_RELAXED,
                         __HIP_MEMORY_SCOPE_AGENT);
  } else {
    if (tid == 0) {
      __hip_atomic_store(arrive + wg * FLAG_STRIDE, epoch, __ATOMIC_RELAXED,
                         __HIP_MEMORY_SCOPE_AGENT);
      while (__hip_atomic_load(go, __ATOMIC_RELAXED,
                               __HIP_MEMORY_SCOPE_AGENT) < epoch) {
        __builtin_amdgcn_s_sleep(1);
      }
    }
    __syncthreads();
  }
}

// ---------------------------------------------------------------------------
// Stage a 6144-float global tile (written via agent-atomic stores) into LDS:
// 192 threads x 16 independent 8B relaxed-agent loads (pipelined; LLC-
// coherent, bypasses stale L2), then 8B LDS writes (2-way bank alias = free).
// ---------------------------------------------------------------------------
__device__ __forceinline__ void stage_tile(const float* gsrc, float* sdst,
                                           int tid) {
  const unsigned long long* src = (const unsigned long long*)gsrc;
  unsigned long long u[16];
#pragma unroll
  for (int j = 0; j < 16; ++j)
    u[j] = __hip_atomic_load(src + tid + j * 192, __ATOMIC_RELAXED,
                             __HIP_MEMORY_SCOPE_AGENT);
  unsigned long long* dst = (unsigned long long*)sdst;
#pragma unroll
  for (int j = 0; j < 16; ++j) dst[tid + j * 192] = u[j];
}

// ---------------------------------------------------------------------------
// Persistent scan kernel. 256 WGs x 192 thr (3 waves). Wave r of WG wg owns
// row jg = wg*3+r of W1/S1/W2/S2/W2T/S2T (all LDS-resident). Cross-WG tiles
// h1g/dOg: written with agent-atomic scalar stores, read via stage_tile into
// sTile once per WG per phase. 2 grid barriers per step.
// ---------------------------------------------------------------------------
__global__ __launch_bounds__(NTHR, 1) void scan_kernel(
    const float* __restrict__ kbuf, const float* __restrict__ vbuf,
    const float* __restrict__ alphaA, const float* __restrict__ etaA,
    const float* __restrict__ MW1, const float* __restrict__ Mb1,
    const float* __restrict__ MW2, const float* __restrict__ Mb2,
    float* __restrict__ W1f, float* __restrict__ b1f, float* __restrict__ W2f,
    float* __restrict__ b2f, float* h1g, float* dOg,
    int* arrive, int* go) {
  __shared__ float sW1[3][768], sS1[3][768], sW2[3][768], sS2[3][768];
  __shared__ float sW2T[3][768], sS2T[3][768];
  __shared__ float sTile[6144];
  __shared__ float sb1[3], ssb1[3], sb2[3], ssb2[3];

  const int tid = threadIdx.x, wg = blockIdx.x;
  const int r = tid >> 6, lane = tid & 63;
  const int jg = wg * 3 + r;
  const int colb = lane * 12;

  // ---- init state ----
  {
    const float4* s1 = (const float4*)(MW1 + (size_t)jg * 768 + colb);
    float4* d1 = (float4*)(&sW1[r][colb]);
    d1[0] = s1[0]; d1[1] = s1[1]; d1[2] = s1[2];
    const float4* s2 = (const float4*)(MW2 + (size_t)jg * 768 + colb);
    float4* d2 = (float4*)(&sW2[r][colb]);
    d2[0] = s2[0]; d2[1] = s2[1]; d2[2] = s2[2];
#pragma unroll
    for (int m = 0; m < 12; ++m)
      sW2T[r][colb + m] = MW2[(size_t)(colb + m) * 768 + jg];
    float4 z4 = {0.f, 0.f, 0.f, 0.f};
    ((float4*)&sS1[r][colb])[0] = z4; ((float4*)&sS1[r][colb])[1] = z4; ((float4*)&sS1[r][colb])[2] = z4;
    ((float4*)&sS2[r][colb])[0] = z4; ((float4*)&sS2[r][colb])[1] = z4; ((float4*)&sS2[r][colb])[2] = z4;
    ((float4*)&sS2T[r][colb])[0] = z4; ((float4*)&sS2T[r][colb])[1] = z4; ((float4*)&sS2T[r][colb])[2] = z4;
    if (lane == 0) {
      sb1[r] = Mb1[jg]; sb2[r] = Mb2[jg];
      ssb1[r] = 0.f; ssb2[r] = 0.f;
    }
  }
  __syncthreads();

  int epoch = 0;
  alignas(16) float ktv[8][12];
  float hprev[8], sgv[8], h1loc[8];
  const float c0 = 2.0f / 6144.0f;

  for (int t = 0; t < S_LEN; ++t) {
    const float a_t = alphaA[t], e_t = etaA[t];
    const float om_a = 1.0f - a_t;

    // k_t rows (registers through phase C) -- read-only, normal cached loads
#pragma unroll
    for (int b = 0; b < 8; ++b) {
      const float4* kp =
          (const float4*)(kbuf + ((size_t)t * 8 + b) * 768 + colb);
      float4 k0 = kp[0], k1 = kp[1], k2 = kp[2];
      ktv[b][0] = k0.x; ktv[b][1] = k0.y; ktv[b][2] = k0.z; ktv[b][3] = k0.w;
      ktv[b][4] = k1.x; ktv[b][5] = k1.y; ktv[b][6] = k1.z; ktv[b][7] = k1.w;
      ktv[b][8] = k2.x; ktv[b][9] = k2.y; ktv[b][10] = k2.z; ktv[b][11] = k2.w;
    }

    // ---- phase A ----
    {
      alignas(16) float w1v[12];
      const float4* wp = (const float4*)(&sW1[r][colb]);
      *(float4*)&w1v[0] = wp[0]; *(float4*)&w1v[4] = wp[1]; *(float4*)&w1v[8] = wp[2];
      float acc[8] = {0, 0, 0, 0, 0, 0, 0, 0};
#pragma unroll
      for (int m = 0; m < 12; ++m)
#pragma unroll
        for (int b = 0; b < 8; ++b) acc[b] = fmaf(ktv[b][m], w1v[m], acc[b]);
#pragma unroll
      for (int off = 32; off > 0; off >>= 1)
#pragma unroll
        for (int b = 0; b < 8; ++b) acc[b] += __shfl_xor(acc[b], off, 64);
      const float b1v = sb1[r];
#pragma unroll
      for (int b = 0; b < 8; ++b) {
        float z = acc[b] + b1v;
        float sg = 1.0f / (1.0f + expf(-z));
        hprev[b] = z; sgv[b] = sg; h1loc[b] = z * sg;
      }
#pragma unroll
      for (int b = 0; b < 8; ++b)
        if (lane == b) st_agent(h1g + b * 768 + jg, h1loc[b]);
    }
    grid_barrier(arrive, go, wg, tid, ++epoch);

    // ---- phase B ----
    {
      stage_tile(h1g, sTile, tid);   // h1 tile -> LDS (once per WG)
      __syncthreads();
      alignas(16) float w2v[12];
      const float4* wp = (const float4*)(&sW2[r][colb]);
      *(float4*)&w2v[0] = wp[0]; *(float4*)&w2v[4] = wp[1]; *(float4*)&w2v[8] = wp[2];
      alignas(16) float hc[8][12];
#pragma unroll
      for (int b = 0; b < 8; ++b) {
        const float4* hp = (const float4*)(&sTile[b * 768 + colb]);
        float4 h0 = hp[0], h1 = hp[1], h2 = hp[2];
        hc[b][0] = h0.x; hc[b][1] = h0.y; hc[b][2] = h0.z; hc[b][3] = h0.w;
        hc[b][4] = h1.x; hc[b][5] = h1.y; hc[b][6] = h1.z; hc[b][7] = h1.w;
        hc[b][8] = h2.x; hc[b][9] = h2.y; hc[b][10] = h2.z; hc[b][11] = h2.w;
      }
      float acc[8] = {0, 0, 0, 0, 0, 0, 0, 0};
#pragma unroll
      for (int m = 0; m < 12; ++m)
#pragma unroll
        for (int b = 0; b < 8; ++b) acc[b] = fmaf(hc[b][m], w2v[m], acc[b]);
#pragma unroll
      for (int off = 32; off > 0; off >>= 1)
#pragma unroll
        for (int b = 0; b < 8; ++b) acc[b] += __shfl_xor(acc[b], off, 64);
      const float b2v = sb2[r];
      float dOv[8];
#pragma unroll
      for (int b = 0; b < 8; ++b) {
        float outv = acc[b] + b2v;
        dOv[b] = c0 * (outv - vbuf[((size_t)t * 8 + b) * 768 + jg]);
      }
#pragma unroll
      for (int b = 0; b < 8; ++b)
        if (lane == b) st_agent(dOg + b * 768 + jg, dOv[b]);
      // W2 row update
#pragma unroll
      for (int m = 0; m < 12; ++m) {
        float g = 0.f;
#pragma unroll
        for (int b = 0; b < 8; ++b) g = fmaf(dOv[b], hc[b][m], g);
        float snew = e_t * sS2[r][colb + m] - THETA_F * g;
        sS2[r][colb + m] = snew;
        sW2[r][colb + m] = om_a * w2v[m] + snew;
      }
      if (lane == 0) {
        float gb = dOv[0] + dOv[1] + dOv[2] + dOv[3] + dOv[4] + dOv[5] + dOv[6] + dOv[7];
        float snew = e_t * ssb2[r] - THETA_F * gb;
        ssb2[r] = snew;
        sb2[r] = om_a * sb2[r] + snew;
      }
    }
    grid_barrier(arrive, go, wg, tid, ++epoch);

    // ---- phase C ----
    {
      stage_tile(dOg, sTile, tid);   // dOut tile -> LDS (once per WG)
      __syncthreads();
      alignas(16) float w2tv[12];
      const float4* wp = (const float4*)(&sW2T[r][colb]);
      *(float4*)&w2tv[0] = wp[0]; *(float4*)&w2tv[4] = wp[1]; *(float4*)&w2tv[8] = wp[2];
      alignas(16) float dc[8][12];
#pragma unroll
      for (int b = 0; b < 8; ++b) {
        const float4* dp = (const float4*)(&sTile[b * 768 + colb]);
        float4 d0 = dp[0], d1 = dp[1], d2 = dp[2];
        dc[b][0] = d0.x; dc[b][1] = d0.y; dc[b][2] = d0.z; dc[b][3] = d0.w;
        dc[b][4] = d1.x; dc[b][5] = d1.y; dc[b][6] = d1.z; dc[b][7] = d1.w;
        dc[b][8] = d2.x; dc[b][9] = d2.y; dc[b][10] = d2.z; dc[b][11] = d2.w;
      }
      float acc[8] = {0, 0, 0, 0, 0, 0, 0, 0};
#pragma unroll
      for (int m = 0; m < 12; ++m)
#pragma unroll
        for (int b = 0; b < 8; ++b) acc[b] = fmaf(dc[b][m], w2tv[m], acc[b]);
#pragma unroll
      for (int off = 32; off > 0; off >>= 1)
#pragma unroll
        for (int b = 0; b < 8; ++b) acc[b] += __shfl_xor(acc[b], off, 64);
      float dpre[8];
#pragma unroll
      for (int b = 0; b < 8; ++b)
        dpre[b] = acc[b] * (sgv[b] * (1.0f + hprev[b] * (1.0f - sgv[b])));
      // W1 row update
#pragma unroll
      for (int m = 0; m < 12; ++m) {
        float g = 0.f;
#pragma unroll
        for (int b = 0; b < 8; ++b) g = fmaf(dpre[b], ktv[b][m], g);
        float snew = e_t * sS1[r][colb + m] - THETA_F * g;
        sS1[r][colb + m] = snew;
        sW1[r][colb + m] = om_a * sW1[r][colb + m] + snew;
      }
      // W2T row update
#pragma unroll
      for (int m = 0; m < 12; ++m) {
        float g = 0.f;
#pragma unroll
        for (int b = 0; b < 8; ++b) g = fmaf(h1loc[b], dc[b][m], g);
        float snew = e_t * sS2T[r][colb + m] - THETA_F * g;
        sS2T[r][colb + m] = snew;
        sW2T[r][colb + m] = om_a * sW2T[r][colb + m] + snew;
      }
      if (lane == 0) {
        float gb = dpre[0] + dpre[1] + dpre[2] + dpre[3] + dpre[4] + dpre[5] + dpre[6] + dpre[7];
        float snew = e_t * ssb1[r] - THETA_F * gb;
        ssb1[r] = snew;
        sb1[r] = om_a * sb1[r] + snew;
      }
    }
    // no barrier before next A: h1g reads (B staging) complete before
    // barrier2; dOg reads (C staging) complete before each WG reaches
    // barrier1(t+1), and dOg is only rewritten after barrier1(t+1).
  }

  // ---- dump final params ----
  {
    float4* d1 = (float4*)(W1f + (size_t)jg * 768 + colb);
    const float4* s1 = (const float4*)(&sW1[r][colb]);
    d1[0] = s1[0]; d1[1] = s1[1]; d1[2] = s1[2];
    float4* d2 = (float4*)(W2f + (size_t)jg * 768 + colb);
    const float4* s2 = (const float4*)(&sW2[r][colb]);
    d2[0] = s2[0]; d2[1] = s2[1]; d2[2] = s2[2];
    if (lane == 0) {
      b1f[jg] = sb1[r];
      b2f[jg] = sb2[r];
    }
  }
}

// ---------------------------------------------------------------------------
extern "C" void kernel_launch(void* const* d_in, const int* in_sizes, int n_in,
                              void* d_out, int out_size, void* d_ws,
                              size_t ws_size, hipStream_t stream) {
  (void)in_sizes; (void)n_in; (void)out_size; (void)ws_size;
  const float* x   = (const float*)d_in[0];
  const float* WKw = (const float*)d_in[1];
  const float* WKb = (const float*)d_in[2];
  const float* WVw = (const float*)d_in[3];
  const float* WVb = (const float*)d_in[4];
  const float* WQw = (const float*)d_in[5];
  const float* WQb = (const float*)d_in[6];
  const float* MW1 = (const float*)d_in[7];
  const float* Mb1 = (const float*)d_in[8];
  const float* MW2 = (const float*)d_in[9];
  const float* Mb2 = (const float*)d_in[10];
  const float* FGW1 = (const float*)d_in[11];
  const float* FGb1 = (const float*)d_in[12];
  const float* FGw2 = (const float*)d_in[13];
  const float* FGb2 = (const float*)d_in[14];
  const float* DGW1 = (const float*)d_in[15];
  const float* DGb1 = (const float*)d_in[16];
  const float* DGw2 = (const float*)d_in[17];
  const float* DGb2 = (const float*)d_in[18];
  float* out = (float*)d_out;

  // workspace layout (floats); q/h1q alias k/v after the scan.
  float* ws = (float*)d_ws;
  float* kbuf = ws;                       // [S,B,D]
  float* vbuf = ws + 6291456;             // [S,B,D]
  float* W1f  = ws + 12582912;            // [768,768]
  float* W2f  = W1f + 589824;
  float* b1f  = W2f + 589824;             // [768]
  float* b2f  = b1f + 768;
  float* alphaA = b2f + 768;              // [1024]
  float* etaA   = alphaA + 1024;
  float* h1g  = etaA + 1024;              // [8,768]
  float* dOg  = h1g + 6144;               // [8,768]
  int* arrive = (int*)(dOg + 6144);       // [NWG*FLAG_STRIDE]
  int* go     = arrive + NWG * FLAG_STRIDE;
  float* qbuf = kbuf;
  float* h1q  = vbuf;

  hipMemsetAsync(arrive, 0, (NWG * FLAG_STRIDE + FLAG_STRIDE) * sizeof(int),
                 stream);

  dim3 gg(12, 64), bb(256);
  gemm_tn<0, 1><<<gg, bb, 0, stream>>>(x, WKw, WKb, kbuf);
  gemm_tn<0, 1><<<gg, bb, 0, stream>>>(x, WVw, WVb, vbuf);
  gates_kernel<<<dim3(1024), dim3(512), 0, stream>>>(
      x, FGW1, FGb1, FGw2, FGb2, DGW1, DGb1, DGw2, DGb2, alphaA, etaA);
  scan_kernel<<<dim3(NWG), dim3(NTHR), 0, stream>>>(
      kbuf, vbuf, alphaA, etaA, MW1, Mb1, MW2, Mb2, W1f, b1f, W2f, b2f, h1g,
      dOg, arrive, go);
  gemm_tn<0, 0><<<gg, bb, 0, stream>>>(x, WQw, WQb, qbuf);
  gemm_tn<1, 0><<<gg, bb, 0, stream>>>(qbuf, W1f, b1f, h1q);
  gemm_tn<0, 0><<<gg, bb, 0, stream>>>(h1q, W2f, b2f, out);
}